// Round 12
// baseline (279.094 us; speedup 1.0000x reference)
//
#include <hip/hip_runtime.h>
#include <hip/hip_bf16.h>

#define NN 100000
#define NE 1600000
#define NBUK 1563          // ceil(NN/64) 64-node dst buckets
#define NBB  196           // histogram/place blocks (8192 edges each)
#define BATCH 8192
#define CNTSZ (NBUK*NBB)   // 306348
#define SCANB 300          // ceil(CNTSZ/1024)
#define CVB   81           // convert blocks (512 thr): 81*512 >= CVTOT

using bf16 = __hip_bfloat16;
typedef unsigned short us8_t __attribute__((ext_vector_type(8)));
typedef short s8v __attribute__((ext_vector_type(8)));     // MFMA bf16 A/B frag (8 bf16)
typedef float f4v __attribute__((ext_vector_type(4)));     // MFMA f32 C/D frag
static __device__ __forceinline__ float b2f(bf16 v){ return __bfloat162float(v); }
static __device__ __forceinline__ bf16 f2b(float v){ return __float2bfloat16(v); }
static __device__ __forceinline__ float us2f(unsigned u){
  unsigned x = u<<16; float f; __builtin_memcpy(&f,&x,4); return f;
}
static __device__ __forceinline__ unsigned short f2us(float v){
  bf16 b = f2b(v); unsigned short u; __builtin_memcpy(&u,&b,2); return u;
}

// canonical f32 weight-pool offsets (floats)
#define W1F   0
#define B1F   128
#define W2F   192
#define B2F   4288
#define W3F   4352
#define B3F   8448
#define FW1F  8512
#define FB1F  16704
#define FW2F  16832
#define FB2F  20928
#define WTOT  20960

// split-bf16 FRAGMENT-CONTIGUOUS weight pools (ushort elements).
// Fragment (c,kk), lane l, elem j lives at ((c*NKK+kk)*64 + l)*8 + j.
// Source element: col = c*16 + (l&15), k = kk*32 + (l>>4)*8 + j.
#define W2TH  0
#define W2TL  4096
#define W3TH  8192
#define W3TL  12288
#define F1TH  16384
#define F1TL  24576
#define F2TH  32768
#define F2TL  36864
#define CVTOT (WTOT + 20480)   // 41440 work items

// ---- merged init: blocks 0..NBB-1 = edge histogram; blocks NBB.. = convert ----
// Convert blocks re-derive the dtype sniff locally (4096 contiguous samples;
// f32 storage -> bf16-exponent field uniform-random, miss P ~ e^-32).
__global__ void k_init(const unsigned short* __restrict__ xr,
                       const void* p0,const void* p1,const void* p2,const void* p3,
                       const void* p4,const void* p5,const void* p6,const void* p7,
                       const void* p8,const void* p9,
                       int* __restrict__ flag, float* __restrict__ Wc,
                       unsigned short* __restrict__ Wb,
                       const int* __restrict__ dstI, int* __restrict__ cnt){
  __shared__ int shm[NBUK];
  int tid = threadIdx.x;
  if(blockIdx.x < NBB){
    // ---- edge histogram into per-(bucket,block) counter matrix ----
    for(int j=tid; j<NBUK; j+=512) shm[j] = 0;
    __syncthreads();
    int e0 = blockIdx.x*BATCH;
    int e1 = min(NE, e0+BATCH);
    int q0 = e0>>2, q1 = e1>>2;
    const int4* d4 = (const int4*)dstI;
    for(int q=q0+tid; q<q1; q+=512){
      int4 d = d4[q];
      atomicAdd(&shm[d.x>>6], 1);
      atomicAdd(&shm[d.y>>6], 1);
      atomicAdd(&shm[d.z>>6], 1);
      atomicAdd(&shm[d.w>>6], 1);
    }
    __syncthreads();
    for(int j=tid; j<NBUK; j+=512) cnt[j*NBB + blockIdx.x] = shm[j];
    return;
  }
  // ---- weight convert (f32 pool + frag-contiguous split-bf16 pool) ----
  if(tid==0) shm[0] = 0;
  __syncthreads();
  int loc = 0;
  #pragma unroll
  for(int i=0;i<8;i++){
    unsigned e = (xr[(tid + i*512)*2]>>7)&0xFF;
    if(e==0xFFu || e==0u) loc = 1;
  }
  if(loc) shm[0] = 1;          // benign same-value race
  __syncthreads();
  int fl = shm[0];
  int bb = blockIdx.x - NBB;
  if(bb==0 && tid==0) *flag = fl;   // consumed by k_bsort
  const void* ps[10] = {p0,p1,p2,p3,p4,p5,p6,p7,p8,p9};
  const int off[11] = {W1F,B1F,W2F,B2F,W3F,B3F,FW1F,FB1F,FW2F,FB2F,WTOT};
  int t = bb*512 + tid;
  if(t < WTOT){
    int seg = 0;
    while(off[seg+1] <= t) seg++;
    int j = t - off[seg];
    Wc[t] = fl ? ((const float*)ps[seg])[j] : b2f(((const bf16*)ps[seg])[j]);
  } else if(t < CVTOT){
    int u = t - WTOT;
    const void* src; int sidx, dhi, dlo;
    if(u < 4096){            // W2: c 0..3, kk 0..1, K stride 64
      int j = u&7, l = (u>>3)&63, ckk = u>>9;
      int c = ckk>>1, kk = ckk&1;
      int col = c*16 + (l&15), k = kk*32 + ((l>>4)<<3) + j;
      src = ps[2]; sidx = k*64 + col;  dhi = W2TH + u; dlo = W2TL + u;
    } else if(u < 8192){     // W3
      int u2 = u-4096;
      int j = u2&7, l = (u2>>3)&63, ckk = u2>>9;
      int c = ckk>>1, kk = ckk&1;
      int col = c*16 + (l&15), k = kk*32 + ((l>>4)<<3) + j;
      src = ps[4]; sidx = k*64 + col;  dhi = W3TH + u2; dlo = W3TL + u2;
    } else if(u < 16384){    // FW1: c 0..7, kk 0..1, K stride 128
      int u2 = u-8192;
      int j = u2&7, l = (u2>>3)&63, ckk = u2>>9;
      int c = ckk>>1, kk = ckk&1;
      int col = c*16 + (l&15), k = kk*32 + ((l>>4)<<3) + j;
      src = ps[6]; sidx = k*128 + col; dhi = F1TH + u2; dlo = F1TL + u2;
    } else {                 // FW2: c 0..1, kk 0..3, K stride 32
      int u2 = u-16384;
      int j = u2&7, l = (u2>>3)&63, ckk = u2>>9;
      int c = ckk>>2, kk = ckk&3;
      int col = c*16 + (l&15), k = kk*32 + ((l>>4)<<3) + j;
      src = ps[8]; sidx = k*32 + col;  dhi = F2TH + u2; dlo = F2TL + u2;
    }
    float v = fl ? ((const float*)src)[sidx] : b2f(((const bf16*)src)[sidx]);
    unsigned short hi = f2us(v);
    Wb[dhi] = hi;
    Wb[dlo] = f2us(v - us2f(hi));
  }
}

__global__ void k_scanA(const int* __restrict__ cnt, int* __restrict__ tmp,
                        int* __restrict__ bsum){
  __shared__ int sh[1024];
  int gi = blockIdx.x*1024 + threadIdx.x;
  int v = (gi < CNTSZ) ? cnt[gi] : 0;
  sh[threadIdx.x] = v; __syncthreads();
  for(int off=1; off<1024; off<<=1){
    int t = (threadIdx.x>=off) ? sh[threadIdx.x-off] : 0;
    __syncthreads();
    sh[threadIdx.x] += t;
    __syncthreads();
  }
  if(gi < CNTSZ) tmp[gi] = sh[threadIdx.x];
  if(threadIdx.x == 1023) bsum[blockIdx.x] = sh[1023];
}
// scanC with scanB folded in: each block tree-reduces bsum[0..blockIdx) locally
__global__ void k_scanC(int* __restrict__ cnt, const int* __restrict__ tmp,
                        const int* __restrict__ bsum, int* __restrict__ bucketStart){
  __shared__ int sh[1024];
  int t = threadIdx.x;
  int b = blockIdx.x;
  sh[t] = (t < b) ? bsum[t] : 0;      // SCANB=300 < 1024
  __syncthreads();
  for(int off=512; off>0; off>>=1){
    if(t < off) sh[t] += sh[t+off];
    __syncthreads();
  }
  int boffb = sh[0];                   // exclusive block offset
  int gi = b*1024 + t;
  if(gi < CNTSZ){
    int orig = cnt[gi];
    int excl = tmp[gi] - orig + boffb;
    cnt[gi] = excl;
    if(gi % NBB == 0) bucketStart[gi/NBB] = excl;
  }
  if(gi == 0) bucketStart[NBUK] = NE;
}
__global__ void k_bplace(const int* __restrict__ src, const int* __restrict__ dst,
                         const int* __restrict__ cnt, int* __restrict__ epk){
  __shared__ int cur[NBUK];
  for(int j=threadIdx.x; j<NBUK; j+=512) cur[j] = cnt[j*NBB + blockIdx.x];
  __syncthreads();
  int e0 = blockIdx.x*BATCH, e1 = min(NE, e0+BATCH);
  int q0 = e0>>2, q1 = e1>>2;
  const int4* d4 = (const int4*)dst;
  const int4* s4 = (const int4*)src;
  for(int q=q0+threadIdx.x; q<q1; q+=512){
    int4 d = d4[q];
    int4 s = s4[q];
    int p0 = atomicAdd(&cur[d.x>>6], 1);
    int p1 = atomicAdd(&cur[d.y>>6], 1);
    int p2 = atomicAdd(&cur[d.z>>6], 1);
    int p3 = atomicAdd(&cur[d.w>>6], 1);
    epk[p0] = (s.x<<6) | (d.x&63);
    epk[p1] = (s.y<<6) | (d.y&63);
    epk[p2] = (s.z<<6) | (d.z&63);
    epk[p3] = (s.w<<6) | (d.w&63);
  }
}
// in-bucket counting sort -> exact CSR (rowptr, srcS) + dinv + xd (fused)
__global__ void k_bsort(const int* __restrict__ bucketStart, const int* __restrict__ epk,
                        int* __restrict__ srcS, int* __restrict__ rowptr,
                        float* __restrict__ dinv, const void* __restrict__ xv,
                        const int* __restrict__ flag, float2* __restrict__ xd){
  __shared__ int hist[64], excl[64], cur[64];
  int tid = threadIdx.x;
  if(tid < 64) hist[tid] = 0;
  __syncthreads();
  int b = blockIdx.x, beg = bucketStart[b], end = bucketStart[b+1];
  for(int p=beg+tid; p<end; p+=512) atomicAdd(&hist[epk[p]&63], 1);
  __syncthreads();
  if(tid == 0){
    int run = 0;
    for(int j=0;j<64;j++){ excl[j] = run; run += hist[j]; }
  }
  __syncthreads();
  if(tid < 64){
    int g = b*64 + tid;
    if(g < NN){
      rowptr[g] = beg + excl[tid];
      float d = rsqrtf((float)(hist[tid] + 1));   // +1 self-loop
      dinv[g]  = d;
      float x0, x1;
      if(*flag){ float2 p = ((const float2*)xv)[g]; x0=p.x; x1=p.y; }
      else     { const bf16* xp=(const bf16*)xv; x0=b2f(xp[2*g]); x1=b2f(xp[2*g+1]); }
      xd[g] = make_float2(x0*d, x1*d);
    }
    cur[tid] = excl[tid];
  }
  if(b == 0 && tid == 0) rowptr[NN] = NE;
  __syncthreads();
  for(int p=beg+tid; p<end; p+=512){
    int pk = epk[p];
    int pos = atomicAdd(&cur[pk&63], 1);
    srcS[beg+pos] = pk>>6;
  }
}

// ---------------- layer 1 fused: propagate x (8B gathers, masked rounds) + 2->64 transform + relu ----------------
__global__ void k_prop1(const int* __restrict__ rowptr, const int* __restrict__ srcS,
                        const float2* __restrict__ xd, const float* __restrict__ Wc,
                        const float* __restrict__ dinv, bf16* __restrict__ h){
  __shared__ float W1s[128];
  __shared__ float bs[64];
  if(threadIdx.x < 128) W1s[threadIdx.x] = Wc[W1F + threadIdx.x];
  if(threadIdx.x < 64)  bs[threadIdx.x]  = Wc[B1F + threadIdx.x];
  __syncthreads();
  int i = blockIdx.x*256 + threadIdx.x;
  if(i >= NN) return;
  int beg = rowptr[i], end = rowptr[i+1];
  float2 self = xd[i];
  float ax[8] = {self.x,0,0,0,0,0,0,0};
  float ay[8] = {self.y,0,0,0,0,0,0,0};
  int last = end - 1;
  for(int p = beg; p < end; p += 8){      // masked 8-wide rounds, no serial tail
    int sI[8];
    #pragma unroll
    for(int j=0;j<8;j++) sI[j] = srcS[min(p+j, last)];
    float2 v[8];
    #pragma unroll
    for(int j=0;j<8;j++) v[j] = xd[sI[j]];
    #pragma unroll
    for(int j=0;j<8;j++){
      if(p+j < end){ ax[j] += v[j].x; ay[j] += v[j].y; }
    }
  }
  float y0 = ((ax[0]+ax[1])+(ax[2]+ax[3]))+((ax[4]+ax[5])+(ax[6]+ax[7]));
  float y1 = ((ay[0]+ay[1])+(ay[2]+ay[3]))+((ay[4]+ay[5])+(ay[6]+ay[7]));
  float d = dinv[i];
  unsigned short* hp = (unsigned short*)h + (size_t)i*64;
  #pragma unroll
  for(int g=0; g<8; g++){
    us8_t o;
    #pragma unroll
    for(int j=0;j<8;j++){
      int c = g*8+j;
      o[j] = f2us(fmaxf(d*(y0*W1s[c] + y1*W1s[64+c]) + bs[c], 0.0f));
    }
    *(us8_t*)(hp + g*8) = o;
  }
}

// ---------------- 64->64 transform, MFMA (frag-contiguous split-bf16 weights) ----------------
__global__ void __launch_bounds__(256) k_transform64(
    const bf16* __restrict__ h, const unsigned short* __restrict__ wth,
    const unsigned short* __restrict__ wtl,
    const float* __restrict__ dinv, bf16* __restrict__ s){
  int tid = threadIdx.x;
  int w = tid>>6, l = tid&63;
  int lr = l&15, lg = l>>4;
  int row0 = blockIdx.x*64 + w*16;
  const unsigned short* hp = (const unsigned short*)h;
  int arow = min(row0 + lr, NN-1);
  s8v a0 = *(const s8v*)(hp + (size_t)arow*64 + lg*8);
  s8v a1 = *(const s8v*)(hp + (size_t)arow*64 + 32 + lg*8);
  f4v z = {0.f,0.f,0.f,0.f};
  f4v acc0=z, acc1=z, acc2=z, acc3=z;
  #define T64_TILE(ACC, C) { \
    int wb0 = (((C)*2+0)*64 + l)*8; \
    int wb1 = (((C)*2+1)*64 + l)*8; \
    s8v bh0 = *(const s8v*)(wth + wb0); \
    s8v bh1 = *(const s8v*)(wth + wb1); \
    s8v bl0 = *(const s8v*)(wtl + wb0); \
    s8v bl1 = *(const s8v*)(wtl + wb1); \
    ACC = __builtin_amdgcn_mfma_f32_16x16x32_bf16(a0, bh0, ACC, 0,0,0); \
    ACC = __builtin_amdgcn_mfma_f32_16x16x32_bf16(a1, bh1, ACC, 0,0,0); \
    ACC = __builtin_amdgcn_mfma_f32_16x16x32_bf16(a0, bl0, ACC, 0,0,0); \
    ACC = __builtin_amdgcn_mfma_f32_16x16x32_bf16(a1, bl1, ACC, 0,0,0); }
  T64_TILE(acc0, 0) T64_TILE(acc1, 1) T64_TILE(acc2, 2) T64_TILE(acc3, 3)
  #undef T64_TILE
  #pragma unroll
  for(int r=0;r<4;r++){
    int orow = row0 + lg*4 + r;
    if(orow < NN){
      float dv = dinv[orow];
      unsigned short* op = (unsigned short*)s + (size_t)orow*64 + lr;
      op[0]  = f2us(acc0[r]*dv);
      op[16] = f2us(acc1[r]*dv);
      op[32] = f2us(acc2[r]*dv);
      op[48] = f2us(acc3[r]*dv);
    }
  }
}

// ---------------- CSR aggregate + finalize: TWO nodes per wave, persistent grid-stride ----------------
__global__ void __launch_bounds__(256) k_aggregate(
    const int* __restrict__ rowptr, const int* __restrict__ srcS,
    const bf16* __restrict__ s, const float* __restrict__ dinv,
    const float* __restrict__ bias, bf16* __restrict__ h){
  int wave = threadIdx.x>>6, lane = threadIdx.x&63;
  int half = lane>>5;                 // which node of the pair
  int lh   = lane&31;
  int slot = lh>>3;                   // 0..3
  int oct  = lane&7;
  const unsigned short* sp = (const unsigned short*)s;
  float4 bA = *(const float4*)(bias + oct*8);
  float4 bB = *(const float4*)(bias + oct*8 + 4);
  float bb[8] = {bA.x,bA.y,bA.z,bA.w,bB.x,bB.y,bB.z,bB.w};
  for(int i0 = blockIdx.x*8; i0 < NN; i0 += gridDim.x*8){   // NN%8==0 -> i<NN always
    int i = i0 + wave*2 + half;
    int beg = rowptr[i], end = rowptr[i+1];
    unsigned deg = (unsigned)(end - beg);
    us8_t sv = *(const us8_t*)(sp + (size_t)i*64 + oct*8);
    float a0[8] = {0,0,0,0,0,0,0,0};
    float a1[8] = {0,0,0,0,0,0,0,0};
    int p0 = beg & ~3;                // aligned round base
    while(__any(p0 < end)){
      if(p0 < end){
        int q  = p0 + slot*4;
        int qc = min(q, NE-4);
        int4 E = *(const int4*)(srcS + qc);
        us8_t v0 = *(const us8_t*)(sp + (size_t)E.x*64 + oct*8);
        us8_t v1 = *(const us8_t*)(sp + (size_t)E.y*64 + oct*8);
        us8_t v2 = *(const us8_t*)(sp + (size_t)E.z*64 + oct*8);
        us8_t v3 = *(const us8_t*)(sp + (size_t)E.w*64 + oct*8);
        unsigned rel = (unsigned)(q - beg);
        if(rel+0u < deg){
          #pragma unroll
          for(int j=0;j<8;j++) a0[j] += us2f(v0[j]);
        }
        if(rel+1u < deg){
          #pragma unroll
          for(int j=0;j<8;j++) a1[j] += us2f(v1[j]);
        }
        if(rel+2u < deg){
          #pragma unroll
          for(int j=0;j<8;j++) a0[j] += us2f(v2[j]);
        }
        if(rel+3u < deg){
          #pragma unroll
          for(int j=0;j<8;j++) a1[j] += us2f(v3[j]);
        }
      }
      p0 += 16;
    }
    float c[8];
    #pragma unroll
    for(int j=0;j<8;j++){
      float v = a0[j] + a1[j];
      v += __shfl_xor(v, 8, 64);
      v += __shfl_xor(v, 16, 64);
      c[j] = v;
    }
    float dv = dinv[i];
    us8_t o;
    #pragma unroll
    for(int j=0;j<8;j++){
      float v = c[j] + us2f(sv[j]);
      o[j] = f2us(fmaxf(fmaf(dv, v, bb[j]), 0.0f));
    }
    if(slot == 0)
      *(us8_t*)((unsigned short*)h + (size_t)i*64 + oct*8) = o;
  }
}

// ---------------- fused fc1+fc2 MFMA (frag-contiguous weights, fc1 tile in LDS) ----------------
__global__ void __launch_bounds__(256) k_fc(const bf16* __restrict__ h,
                                            const unsigned short* __restrict__ w1h,
                                            const unsigned short* __restrict__ w1l,
                                            const unsigned short* __restrict__ w2h,
                                            const unsigned short* __restrict__ w2l,
                                            const float* __restrict__ Wc,
                                            const int* __restrict__ flag,
                                            void* __restrict__ outv){
  __shared__ __align__(16) unsigned short fs[64][140];   // pad: ~2-way banks in phase 2
  int tid = threadIdx.x;
  int w = tid>>6, l = tid&63;
  int lr = l&15, lg = l>>4;
  int row0 = blockIdx.x*64 + w*16;
  const unsigned short* hp = (const unsigned short*)h;
  int arow = min(row0 + lr, NN-1);
  // ---- phase 1: fc1 (64 -> 128), relu, into LDS ----
  {
    s8v a0 = *(const s8v*)(hp + (size_t)arow*64 + lg*8);
    s8v a1 = *(const s8v*)(hp + (size_t)arow*64 + 32 + lg*8);
    f4v z = {0.f,0.f,0.f,0.f};
    f4v acc[8] = {z,z,z,z,z,z,z,z};
    float bias[8];
    #pragma unroll
    for(int c=0;c<8;c++){
      int wb0 = ((c*2+0)*64 + l)*8;
      int wb1 = ((c*2+1)*64 + l)*8;
      s8v bh0 = *(const s8v*)(w1h + wb0);
      s8v bh1 = *(const s8v*)(w1h + wb1);
      s8v bl0 = *(const s8v*)(w1l + wb0);
      s8v bl1 = *(const s8v*)(w1l + wb1);
      acc[c] = __builtin_amdgcn_mfma_f32_16x16x32_bf16(a0, bh0, acc[c], 0,0,0);
      acc[c] = __builtin_amdgcn_mfma_f32_16x16x32_bf16(a1, bh1, acc[c], 0,0,0);
      acc[c] = __builtin_amdgcn_mfma_f32_16x16x32_bf16(a0, bl0, acc[c], 0,0,0);
      acc[c] = __builtin_amdgcn_mfma_f32_16x16x32_bf16(a1, bl1, acc[c], 0,0,0);
      bias[c] = Wc[FB1F + c*16 + lr];
    }
    #pragma unroll
    for(int r=0;r<4;r++){
      int lrow = w*16 + lg*4 + r;
      #pragma unroll
      for(int c=0;c<8;c++)
        fs[lrow][c*16 + lr] = f2us(fmaxf(acc[c][r] + bias[c], 0.0f));
    }
  }
  __syncthreads();
  // ---- phase 2: fc2 (128 -> 32) from LDS ----
  int lrow = w*16 + lr;
  s8v a0 = *(const s8v*)&fs[lrow][lg*8];
  s8v a1 = *(const s8v*)&fs[lrow][32 + lg*8];
  s8v a2 = *(const s8v*)&fs[lrow][64 + lg*8];
  s8v a3 = *(const s8v*)&fs[lrow][96 + lg*8];
  f4v z = {0.f,0.f,0.f,0.f};
  f4v acc[2] = {z,z};
  float bias[2];
  #pragma unroll
  for(int c=0;c<2;c++){
    int wb0 = ((c*4+0)*64 + l)*8;
    int wb1 = ((c*4+1)*64 + l)*8;
    int wb2 = ((c*4+2)*64 + l)*8;
    int wb3 = ((c*4+3)*64 + l)*8;
    s8v bh0 = *(const s8v*)(w2h + wb0);
    s8v bh1 = *(const s8v*)(w2h + wb1);
    s8v bh2 = *(const s8v*)(w2h + wb2);
    s8v bh3 = *(const s8v*)(w2h + wb3);
    s8v bl0 = *(const s8v*)(w2l + wb0);
    s8v bl1 = *(const s8v*)(w2l + wb1);
    s8v bl2 = *(const s8v*)(w2l + wb2);
    s8v bl3 = *(const s8v*)(w2l + wb3);
    acc[c] = __builtin_amdgcn_mfma_f32_16x16x32_bf16(a0, bh0, acc[c], 0,0,0);
    acc[c] = __builtin_amdgcn_mfma_f32_16x16x32_bf16(a1, bh1, acc[c], 0,0,0);
    acc[c] = __builtin_amdgcn_mfma_f32_16x16x32_bf16(a2, bh2, acc[c], 0,0,0);
    acc[c] = __builtin_amdgcn_mfma_f32_16x16x32_bf16(a3, bh3, acc[c], 0,0,0);
    acc[c] = __builtin_amdgcn_mfma_f32_16x16x32_bf16(a0, bl0, acc[c], 0,0,0);
    acc[c] = __builtin_amdgcn_mfma_f32_16x16x32_bf16(a1, bl1, acc[c], 0,0,0);
    acc[c] = __builtin_amdgcn_mfma_f32_16x16x32_bf16(a2, bl2, acc[c], 0,0,0);
    acc[c] = __builtin_amdgcn_mfma_f32_16x16x32_bf16(a3, bl3, acc[c], 0,0,0);
    bias[c] = Wc[FB2F + c*16 + lr];
  }
  int fl = *flag;
  #pragma unroll
  for(int r=0;r<4;r++){
    int orow = blockIdx.x*64 + w*16 + lg*4 + r;
    if(orow < NN){
      if(fl){
        float* op = (float*)outv + (size_t)orow*32 + lr;
        op[0]  = acc[0][r] + bias[0];
        op[16] = acc[1][r] + bias[1];
      } else {
        unsigned short* op = (unsigned short*)outv + (size_t)orow*32 + lr;
        op[0]  = f2us(acc[0][r] + bias[0]);
        op[16] = f2us(acc[1][r] + bias[1]);
      }
    }
  }
}

extern "C" void kernel_launch(void* const* d_in, const int* in_sizes, int n_in,
                              void* d_out, int out_size, void* d_ws, size_t ws_size,
                              hipStream_t stream){
  const void* x   = d_in[0];
  const int*  ei  = (const int*)d_in[1];
  const int* srcI = ei;        // edge_index[0]
  const int* dstI = ei + NE;   // edge_index[1]

  // workspace layout (bytes); ~43 MB + 80KB bf16 weight pool
  char*   base   = (char*)d_ws;
  int*    flag   = (int*)   (base + 0);          // 256
  float*  Wc     = (float*) (base + 256);        // 83840 -> 84096
  int*    bstart = (int*)   (base + 84224);      // 6256
  int*    cnt    = (int*)   (base + 90624);      // 1225392
  int*    tmpS   = (int*)   (base + 1316096);    // 1225392
  int*    bsum   = (int*)   (base + 2541568);    // 2048
  float*  dinv   = (float*) (base + 2545664);    // 400000
  int*    rowptr = (int*)   (base + 2945664);    // 400004
  int*    epk    = (int*)   (base + 3345792);    // 6400000
  int*    srcS   = (int*)   (base + 9745792);    // 6400000
  float2* xd     = (float2*)(base + 16145792);   // 800000
  bf16*   s      = (bf16*)  (base + 16945792);   // 12800000
  bf16*   h      = (bf16*)  (base + 29745792);   // 12800000 -> ends 42545792
  unsigned short* Wb = (unsigned short*)(base + 42545792);  // 81920 -> ends 42627712

  // merged init: edge histogram (blocks 0..195) + weight convert (blocks 196..276)
  k_init<<<NBB+CVB, 512, 0, stream>>>(
      (const unsigned short*)x,
      d_in[2], d_in[3], d_in[4], d_in[5], d_in[6],
      d_in[7], d_in[8], d_in[9], d_in[10], d_in[11], flag, Wc, Wb, dstI, cnt);

  // bucket-grouped build: scan (2 kernels) -> place -> in-bucket sort (+xd)
  k_scanA <<<SCANB, 1024, 0, stream>>>(cnt, tmpS, bsum);
  k_scanC <<<SCANB, 1024, 0, stream>>>(cnt, tmpS, bsum, bstart);
  k_bplace<<<NBB, 512, 0, stream>>>(srcI, dstI, cnt, epk);
  k_bsort <<<NBUK, 512, 0, stream>>>(bstart, epk, srcS, rowptr, dinv, x, flag, xd);

  // layer 1 (2 -> 64): fused propagate + transform + relu
  k_prop1<<<(NN+255)/256, 256, 0, stream>>>(rowptr, srcS, xd, Wc, dinv, h);

  // layer 2 (64 -> 64)
  k_transform64<<<NBUK, 256, 0, stream>>>(h, Wb+W2TH, Wb+W2TL, dinv, s);
  k_aggregate  <<<2048, 256, 0, stream>>>(rowptr, srcS, s, dinv, Wc+B2F, h);

  // layer 3 (64 -> 64)
  k_transform64<<<NBUK, 256, 0, stream>>>(h, Wb+W3TH, Wb+W3TL, dinv, s);
  k_aggregate  <<<2048, 256, 0, stream>>>(rowptr, srcS, s, dinv, Wc+B3F, h);

  // fused fc1+fc2 (MFMA, frag-contiguous weights, fc1 tile in LDS)
  k_fc<<<NBUK, 256, 0, stream>>>(h, Wb+F1TH, Wb+F1TL, Wb+F2TH, Wb+F2TL, Wc, flag, d_out);
}

// Round 13
// 255.196 us; speedup vs baseline: 1.0936x; 1.0936x over previous
//
#include <hip/hip_runtime.h>
#include <hip/hip_bf16.h>

#define NN 100000
#define NE 1600000
#define NBUK 1563          // ceil(NN/64) 64-node dst buckets
#define NBB  196           // histogram/place blocks (8192 edges each)
#define BATCH 8192
#define CNTSZ (NBUK*NBB)   // 306348
#define SCANB 300          // ceil(CNTSZ/1024)
#define CVB   81           // convert blocks (512 thr): 81*512 >= CVTOT

using bf16 = __hip_bfloat16;
typedef unsigned short us8_t __attribute__((ext_vector_type(8)));
typedef short s8v __attribute__((ext_vector_type(8)));     // MFMA bf16 A/B frag (8 bf16)
typedef float f4v __attribute__((ext_vector_type(4)));     // MFMA f32 C/D frag
static __device__ __forceinline__ float b2f(bf16 v){ return __bfloat162float(v); }
static __device__ __forceinline__ bf16 f2b(float v){ return __float2bfloat16(v); }
static __device__ __forceinline__ float us2f(unsigned u){
  unsigned x = u<<16; float f; __builtin_memcpy(&f,&x,4); return f;
}
static __device__ __forceinline__ unsigned short f2us(float v){
  bf16 b = f2b(v); unsigned short u; __builtin_memcpy(&u,&b,2); return u;
}

// canonical f32 weight-pool offsets (floats)
#define W1F   0
#define B1F   128
#define W2F   192
#define B2F   4288
#define W3F   4352
#define B3F   8448
#define FW1F  8512
#define FB1F  16704
#define FW2F  16832
#define FB2F  20928
#define WTOT  20960

// split-bf16 FRAGMENT-CONTIGUOUS weight pools (ushort elements).
// Fragment (c,kk), lane l, elem j lives at ((c*NKK+kk)*64 + l)*8 + j.
// Source element: col = c*16 + (l&15), k = kk*32 + (l>>4)*8 + j.
#define W2TH  0
#define W2TL  4096
#define W3TH  8192
#define W3TL  12288
#define F1TH  16384
#define F1TL  24576
#define F2TH  32768
#define F2TL  36864
#define CVTOT (WTOT + 20480)   // 41440 work items

// ---- merged init: blocks 0..NBB-1 = edge histogram; blocks NBB.. = convert ----
// Convert blocks re-derive the dtype sniff locally (4096 contiguous samples;
// f32 storage -> bf16-exponent field uniform-random, miss P ~ e^-32).
__global__ void k_init(const unsigned short* __restrict__ xr,
                       const void* p0,const void* p1,const void* p2,const void* p3,
                       const void* p4,const void* p5,const void* p6,const void* p7,
                       const void* p8,const void* p9,
                       int* __restrict__ flag, float* __restrict__ Wc,
                       unsigned short* __restrict__ Wb,
                       const int* __restrict__ dstI, int* __restrict__ cnt){
  __shared__ int shm[NBUK];
  int tid = threadIdx.x;
  if(blockIdx.x < NBB){
    // ---- edge histogram into per-(bucket,block) counter matrix ----
    for(int j=tid; j<NBUK; j+=512) shm[j] = 0;
    __syncthreads();
    int e0 = blockIdx.x*BATCH;
    int e1 = min(NE, e0+BATCH);
    int q0 = e0>>2, q1 = e1>>2;
    const int4* d4 = (const int4*)dstI;
    for(int q=q0+tid; q<q1; q+=512){
      int4 d = d4[q];
      atomicAdd(&shm[d.x>>6], 1);
      atomicAdd(&shm[d.y>>6], 1);
      atomicAdd(&shm[d.z>>6], 1);
      atomicAdd(&shm[d.w>>6], 1);
    }
    __syncthreads();
    for(int j=tid; j<NBUK; j+=512) cnt[j*NBB + blockIdx.x] = shm[j];
    return;
  }
  // ---- weight convert (f32 pool + frag-contiguous split-bf16 pool) ----
  if(tid==0) shm[0] = 0;
  __syncthreads();
  int loc = 0;
  #pragma unroll
  for(int i=0;i<8;i++){
    unsigned e = (xr[(tid + i*512)*2]>>7)&0xFF;
    if(e==0xFFu || e==0u) loc = 1;
  }
  if(loc) shm[0] = 1;          // benign same-value race
  __syncthreads();
  int fl = shm[0];
  int bb = blockIdx.x - NBB;
  if(bb==0 && tid==0) *flag = fl;   // consumed by k_bsort
  const void* ps[10] = {p0,p1,p2,p3,p4,p5,p6,p7,p8,p9};
  const int off[11] = {W1F,B1F,W2F,B2F,W3F,B3F,FW1F,FB1F,FW2F,FB2F,WTOT};
  int t = bb*512 + tid;
  if(t < WTOT){
    int seg = 0;
    while(off[seg+1] <= t) seg++;
    int j = t - off[seg];
    Wc[t] = fl ? ((const float*)ps[seg])[j] : b2f(((const bf16*)ps[seg])[j]);
  } else if(t < CVTOT){
    int u = t - WTOT;
    const void* src; int sidx, dhi, dlo;
    if(u < 4096){            // W2: c 0..3, kk 0..1, K stride 64
      int j = u&7, l = (u>>3)&63, ckk = u>>9;
      int c = ckk>>1, kk = ckk&1;
      int col = c*16 + (l&15), k = kk*32 + ((l>>4)<<3) + j;
      src = ps[2]; sidx = k*64 + col;  dhi = W2TH + u; dlo = W2TL + u;
    } else if(u < 8192){     // W3
      int u2 = u-4096;
      int j = u2&7, l = (u2>>3)&63, ckk = u2>>9;
      int c = ckk>>1, kk = ckk&1;
      int col = c*16 + (l&15), k = kk*32 + ((l>>4)<<3) + j;
      src = ps[4]; sidx = k*64 + col;  dhi = W3TH + u2; dlo = W3TL + u2;
    } else if(u < 16384){    // FW1: c 0..7, kk 0..1, K stride 128
      int u2 = u-8192;
      int j = u2&7, l = (u2>>3)&63, ckk = u2>>9;
      int c = ckk>>1, kk = ckk&1;
      int col = c*16 + (l&15), k = kk*32 + ((l>>4)<<3) + j;
      src = ps[6]; sidx = k*128 + col; dhi = F1TH + u2; dlo = F1TL + u2;
    } else {                 // FW2: c 0..1, kk 0..3, K stride 32
      int u2 = u-16384;
      int j = u2&7, l = (u2>>3)&63, ckk = u2>>9;
      int c = ckk>>2, kk = ckk&3;
      int col = c*16 + (l&15), k = kk*32 + ((l>>4)<<3) + j;
      src = ps[8]; sidx = k*32 + col;  dhi = F2TH + u2; dlo = F2TL + u2;
    }
    float v = fl ? ((const float*)src)[sidx] : b2f(((const bf16*)src)[sidx]);
    unsigned short hi = f2us(v);
    Wb[dhi] = hi;
    Wb[dlo] = f2us(v - us2f(hi));
  }
}

__global__ void k_scanA(const int* __restrict__ cnt, int* __restrict__ tmp,
                        int* __restrict__ bsum){
  __shared__ int sh[1024];
  int gi = blockIdx.x*1024 + threadIdx.x;
  int v = (gi < CNTSZ) ? cnt[gi] : 0;
  sh[threadIdx.x] = v; __syncthreads();
  for(int off=1; off<1024; off<<=1){
    int t = (threadIdx.x>=off) ? sh[threadIdx.x-off] : 0;
    __syncthreads();
    sh[threadIdx.x] += t;
    __syncthreads();
  }
  if(gi < CNTSZ) tmp[gi] = sh[threadIdx.x];
  if(threadIdx.x == 1023) bsum[blockIdx.x] = sh[1023];
}
// scanC with scanB folded in: each block tree-reduces bsum[0..blockIdx) locally
__global__ void k_scanC(int* __restrict__ cnt, const int* __restrict__ tmp,
                        const int* __restrict__ bsum, int* __restrict__ bucketStart){
  __shared__ int sh[1024];
  int t = threadIdx.x;
  int b = blockIdx.x;
  sh[t] = (t < b) ? bsum[t] : 0;      // SCANB=300 < 1024
  __syncthreads();
  for(int off=512; off>0; off>>=1){
    if(t < off) sh[t] += sh[t+off];
    __syncthreads();
  }
  int boffb = sh[0];                   // exclusive block offset
  int gi = b*1024 + t;
  if(gi < CNTSZ){
    int orig = cnt[gi];
    int excl = tmp[gi] - orig + boffb;
    cnt[gi] = excl;
    if(gi % NBB == 0) bucketStart[gi/NBB] = excl;
  }
  if(gi == 0) bucketStart[NBUK] = NE;
}
__global__ void k_bplace(const int* __restrict__ src, const int* __restrict__ dst,
                         const int* __restrict__ cnt, int* __restrict__ epk){
  __shared__ int cur[NBUK];
  for(int j=threadIdx.x; j<NBUK; j+=512) cur[j] = cnt[j*NBB + blockIdx.x];
  __syncthreads();
  int e0 = blockIdx.x*BATCH, e1 = min(NE, e0+BATCH);
  int q0 = e0>>2, q1 = e1>>2;
  const int4* d4 = (const int4*)dst;
  const int4* s4 = (const int4*)src;
  for(int q=q0+threadIdx.x; q<q1; q+=512){
    int4 d = d4[q];
    int4 s = s4[q];
    int p0 = atomicAdd(&cur[d.x>>6], 1);
    int p1 = atomicAdd(&cur[d.y>>6], 1);
    int p2 = atomicAdd(&cur[d.z>>6], 1);
    int p3 = atomicAdd(&cur[d.w>>6], 1);
    epk[p0] = (s.x<<6) | (d.x&63);
    epk[p1] = (s.y<<6) | (d.y&63);
    epk[p2] = (s.z<<6) | (d.z&63);
    epk[p3] = (s.w<<6) | (d.w&63);
  }
}
// in-bucket counting sort -> exact CSR (rowptr, srcS) + dinv + xd (fused)
__global__ void k_bsort(const int* __restrict__ bucketStart, const int* __restrict__ epk,
                        int* __restrict__ srcS, int* __restrict__ rowptr,
                        float* __restrict__ dinv, const void* __restrict__ xv,
                        const int* __restrict__ flag, float2* __restrict__ xd){
  __shared__ int hist[64], excl[64], cur[64];
  int tid = threadIdx.x;
  if(tid < 64) hist[tid] = 0;
  __syncthreads();
  int b = blockIdx.x, beg = bucketStart[b], end = bucketStart[b+1];
  for(int p=beg+tid; p<end; p+=512) atomicAdd(&hist[epk[p]&63], 1);
  __syncthreads();
  if(tid == 0){
    int run = 0;
    for(int j=0;j<64;j++){ excl[j] = run; run += hist[j]; }
  }
  __syncthreads();
  if(tid < 64){
    int g = b*64 + tid;
    if(g < NN){
      rowptr[g] = beg + excl[tid];
      float d = rsqrtf((float)(hist[tid] + 1));   // +1 self-loop
      dinv[g]  = d;
      float x0, x1;
      if(*flag){ float2 p = ((const float2*)xv)[g]; x0=p.x; x1=p.y; }
      else     { const bf16* xp=(const bf16*)xv; x0=b2f(xp[2*g]); x1=b2f(xp[2*g+1]); }
      xd[g] = make_float2(x0*d, x1*d);
    }
    cur[tid] = excl[tid];
  }
  if(b == 0 && tid == 0) rowptr[NN] = NE;
  __syncthreads();
  for(int p=beg+tid; p<end; p+=512){
    int pk = epk[p];
    int pos = atomicAdd(&cur[pk&63], 1);
    srcS[beg+pos] = pk>>6;
  }
}

// ---------------- layer 1 fused: propagate x (8B gathers, masked rounds) + 2->64 transform + relu ----------------
__global__ void k_prop1(const int* __restrict__ rowptr, const int* __restrict__ srcS,
                        const float2* __restrict__ xd, const float* __restrict__ Wc,
                        const float* __restrict__ dinv, bf16* __restrict__ h){
  __shared__ float W1s[128];
  __shared__ float bs[64];
  if(threadIdx.x < 128) W1s[threadIdx.x] = Wc[W1F + threadIdx.x];
  if(threadIdx.x < 64)  bs[threadIdx.x]  = Wc[B1F + threadIdx.x];
  __syncthreads();
  int i = blockIdx.x*256 + threadIdx.x;
  if(i >= NN) return;
  int beg = rowptr[i], end = rowptr[i+1];
  float2 self = xd[i];
  float ax[8] = {self.x,0,0,0,0,0,0,0};
  float ay[8] = {self.y,0,0,0,0,0,0,0};
  int last = end - 1;
  for(int p = beg; p < end; p += 8){      // masked 8-wide rounds, no serial tail
    int sI[8];
    #pragma unroll
    for(int j=0;j<8;j++) sI[j] = srcS[min(p+j, last)];
    float2 v[8];
    #pragma unroll
    for(int j=0;j<8;j++) v[j] = xd[sI[j]];
    #pragma unroll
    for(int j=0;j<8;j++){
      if(p+j < end){ ax[j] += v[j].x; ay[j] += v[j].y; }
    }
  }
  float y0 = ((ax[0]+ax[1])+(ax[2]+ax[3]))+((ax[4]+ax[5])+(ax[6]+ax[7]));
  float y1 = ((ay[0]+ay[1])+(ay[2]+ay[3]))+((ay[4]+ay[5])+(ay[6]+ay[7]));
  float d = dinv[i];
  unsigned short* hp = (unsigned short*)h + (size_t)i*64;
  #pragma unroll
  for(int g=0; g<8; g++){
    us8_t o;
    #pragma unroll
    for(int j=0;j<8;j++){
      int c = g*8+j;
      o[j] = f2us(fmaxf(d*(y0*W1s[c] + y1*W1s[64+c]) + bs[c], 0.0f));
    }
    *(us8_t*)(hp + g*8) = o;
  }
}

// ---------------- 64->64 transform, MFMA (frag-contiguous split-bf16 weights) ----------------
__global__ void __launch_bounds__(256) k_transform64(
    const bf16* __restrict__ h, const unsigned short* __restrict__ wth,
    const unsigned short* __restrict__ wtl,
    const float* __restrict__ dinv, bf16* __restrict__ s){
  int tid = threadIdx.x;
  int w = tid>>6, l = tid&63;
  int lr = l&15, lg = l>>4;
  int row0 = blockIdx.x*64 + w*16;
  const unsigned short* hp = (const unsigned short*)h;
  int arow = min(row0 + lr, NN-1);
  s8v a0 = *(const s8v*)(hp + (size_t)arow*64 + lg*8);
  s8v a1 = *(const s8v*)(hp + (size_t)arow*64 + 32 + lg*8);
  f4v z = {0.f,0.f,0.f,0.f};
  f4v acc0=z, acc1=z, acc2=z, acc3=z;
  #define T64_TILE(ACC, C) { \
    int wb0 = (((C)*2+0)*64 + l)*8; \
    int wb1 = (((C)*2+1)*64 + l)*8; \
    s8v bh0 = *(const s8v*)(wth + wb0); \
    s8v bh1 = *(const s8v*)(wth + wb1); \
    s8v bl0 = *(const s8v*)(wtl + wb0); \
    s8v bl1 = *(const s8v*)(wtl + wb1); \
    ACC = __builtin_amdgcn_mfma_f32_16x16x32_bf16(a0, bh0, ACC, 0,0,0); \
    ACC = __builtin_amdgcn_mfma_f32_16x16x32_bf16(a1, bh1, ACC, 0,0,0); \
    ACC = __builtin_amdgcn_mfma_f32_16x16x32_bf16(a0, bl0, ACC, 0,0,0); \
    ACC = __builtin_amdgcn_mfma_f32_16x16x32_bf16(a1, bl1, ACC, 0,0,0); }
  T64_TILE(acc0, 0) T64_TILE(acc1, 1) T64_TILE(acc2, 2) T64_TILE(acc3, 3)
  #undef T64_TILE
  #pragma unroll
  for(int r=0;r<4;r++){
    int orow = row0 + lg*4 + r;
    if(orow < NN){
      float dv = dinv[orow];
      unsigned short* op = (unsigned short*)s + (size_t)orow*64 + lr;
      op[0]  = f2us(acc0[r]*dv);
      op[16] = f2us(acc1[r]*dv);
      op[32] = f2us(acc2[r]*dv);
      op[48] = f2us(acc3[r]*dv);
    }
  }
}

// ---------------- CSR aggregate + finalize: TWO nodes per wave (R2 form, FROZEN) ----------------
// Measured optimum: 12500 blocks, VGPR 28, ~68% occupancy, ~38.8 us.
// Persistent grid-stride (R11) regressed to 49 us (VGPR 44, occ 37%) — do not
// change launch/occupancy shape.
__global__ void __launch_bounds__(256) k_aggregate(
    const int* __restrict__ rowptr, const int* __restrict__ srcS,
    const bf16* __restrict__ s, const float* __restrict__ dinv,
    const float* __restrict__ bias, bf16* __restrict__ h){
  int wave = threadIdx.x>>6, lane = threadIdx.x&63;
  int half = lane>>5;                 // which node of the pair
  int lh   = lane&31;
  int slot = lh>>3;                   // 0..3
  int oct  = lane&7;
  int i = blockIdx.x*8 + wave*2 + half;   // grid = NN/8 = 12500 blocks
  int beg = rowptr[i], end = rowptr[i+1];
  unsigned deg = (unsigned)(end - beg);
  const unsigned short* sp = (const unsigned short*)s;
  us8_t sv = *(const us8_t*)(sp + (size_t)i*64 + oct*8);
  float a0[8] = {0,0,0,0,0,0,0,0};
  float a1[8] = {0,0,0,0,0,0,0,0};
  int p0 = beg & ~3;                  // aligned round base
  while(__any(p0 < end)){
    if(p0 < end){
      int q  = p0 + slot*4;
      int qc = min(q, NE-4);
      int4 E = *(const int4*)(srcS + qc);
      us8_t v0 = *(const us8_t*)(sp + (size_t)E.x*64 + oct*8);
      us8_t v1 = *(const us8_t*)(sp + (size_t)E.y*64 + oct*8);
      us8_t v2 = *(const us8_t*)(sp + (size_t)E.z*64 + oct*8);
      us8_t v3 = *(const us8_t*)(sp + (size_t)E.w*64 + oct*8);
      unsigned rel = (unsigned)(q - beg);
      if(rel+0u < deg){
        #pragma unroll
        for(int j=0;j<8;j++) a0[j] += us2f(v0[j]);
      }
      if(rel+1u < deg){
        #pragma unroll
        for(int j=0;j<8;j++) a1[j] += us2f(v1[j]);
      }
      if(rel+2u < deg){
        #pragma unroll
        for(int j=0;j<8;j++) a0[j] += us2f(v2[j]);
      }
      if(rel+3u < deg){
        #pragma unroll
        for(int j=0;j<8;j++) a1[j] += us2f(v3[j]);
      }
    }
    p0 += 16;
  }
  float c[8];
  #pragma unroll
  for(int j=0;j<8;j++){
    float v = a0[j] + a1[j];
    v += __shfl_xor(v, 8, 64);
    v += __shfl_xor(v, 16, 64);
    c[j] = v;
  }
  float dv = dinv[i];
  float4 bA = *(const float4*)(bias + oct*8);
  float4 bB = *(const float4*)(bias + oct*8 + 4);
  float bb[8] = {bA.x,bA.y,bA.z,bA.w,bB.x,bB.y,bB.z,bB.w};
  us8_t o;
  #pragma unroll
  for(int j=0;j<8;j++){
    float v = c[j] + us2f(sv[j]);
    o[j] = f2us(fmaxf(fmaf(dv, v, bb[j]), 0.0f));
  }
  if(slot == 0)
    *(us8_t*)((unsigned short*)h + (size_t)i*64 + oct*8) = o;
}

// ---------------- fused fc1+fc2 MFMA (frag-contiguous weights, fc1 tile in LDS) ----------------
__global__ void __launch_bounds__(256) k_fc(const bf16* __restrict__ h,
                                            const unsigned short* __restrict__ w1h,
                                            const unsigned short* __restrict__ w1l,
                                            const unsigned short* __restrict__ w2h,
                                            const unsigned short* __restrict__ w2l,
                                            const float* __restrict__ Wc,
                                            const int* __restrict__ flag,
                                            void* __restrict__ outv){
  __shared__ __align__(16) unsigned short fs[64][140];   // pad: ~2-way banks in phase 2
  int tid = threadIdx.x;
  int w = tid>>6, l = tid&63;
  int lr = l&15, lg = l>>4;
  int row0 = blockIdx.x*64 + w*16;
  const unsigned short* hp = (const unsigned short*)h;
  int arow = min(row0 + lr, NN-1);
  // ---- phase 1: fc1 (64 -> 128), relu, into LDS ----
  {
    s8v a0 = *(const s8v*)(hp + (size_t)arow*64 + lg*8);
    s8v a1 = *(const s8v*)(hp + (size_t)arow*64 + 32 + lg*8);
    f4v z = {0.f,0.f,0.f,0.f};
    f4v acc[8] = {z,z,z,z,z,z,z,z};
    float bias[8];
    #pragma unroll
    for(int c=0;c<8;c++){
      int wb0 = ((c*2+0)*64 + l)*8;
      int wb1 = ((c*2+1)*64 + l)*8;
      s8v bh0 = *(const s8v*)(w1h + wb0);
      s8v bh1 = *(const s8v*)(w1h + wb1);
      s8v bl0 = *(const s8v*)(w1l + wb0);
      s8v bl1 = *(const s8v*)(w1l + wb1);
      acc[c] = __builtin_amdgcn_mfma_f32_16x16x32_bf16(a0, bh0, acc[c], 0,0,0);
      acc[c] = __builtin_amdgcn_mfma_f32_16x16x32_bf16(a1, bh1, acc[c], 0,0,0);
      acc[c] = __builtin_amdgcn_mfma_f32_16x16x32_bf16(a0, bl0, acc[c], 0,0,0);
      acc[c] = __builtin_amdgcn_mfma_f32_16x16x32_bf16(a1, bl1, acc[c], 0,0,0);
      bias[c] = Wc[FB1F + c*16 + lr];
    }
    #pragma unroll
    for(int r=0;r<4;r++){
      int lrow = w*16 + lg*4 + r;
      #pragma unroll
      for(int c=0;c<8;c++)
        fs[lrow][c*16 + lr] = f2us(fmaxf(acc[c][r] + bias[c], 0.0f));
    }
  }
  __syncthreads();
  // ---- phase 2: fc2 (128 -> 32) from LDS ----
  int lrow = w*16 + lr;
  s8v a0 = *(const s8v*)&fs[lrow][lg*8];
  s8v a1 = *(const s8v*)&fs[lrow][32 + lg*8];
  s8v a2 = *(const s8v*)&fs[lrow][64 + lg*8];
  s8v a3 = *(const s8v*)&fs[lrow][96 + lg*8];
  f4v z = {0.f,0.f,0.f,0.f};
  f4v acc[2] = {z,z};
  float bias[2];
  #pragma unroll
  for(int c=0;c<2;c++){
    int wb0 = ((c*4+0)*64 + l)*8;
    int wb1 = ((c*4+1)*64 + l)*8;
    int wb2 = ((c*4+2)*64 + l)*8;
    int wb3 = ((c*4+3)*64 + l)*8;
    s8v bh0 = *(const s8v*)(w2h + wb0);
    s8v bh1 = *(const s8v*)(w2h + wb1);
    s8v bh2 = *(const s8v*)(w2h + wb2);
    s8v bh3 = *(const s8v*)(w2h + wb3);
    s8v bl0 = *(const s8v*)(w2l + wb0);
    s8v bl1 = *(const s8v*)(w2l + wb1);
    s8v bl2 = *(const s8v*)(w2l + wb2);
    s8v bl3 = *(const s8v*)(w2l + wb3);
    acc[c] = __builtin_amdgcn_mfma_f32_16x16x32_bf16(a0, bh0, acc[c], 0,0,0);
    acc[c] = __builtin_amdgcn_mfma_f32_16x16x32_bf16(a1, bh1, acc[c], 0,0,0);
    acc[c] = __builtin_amdgcn_mfma_f32_16x16x32_bf16(a2, bh2, acc[c], 0,0,0);
    acc[c] = __builtin_amdgcn_mfma_f32_16x16x32_bf16(a3, bh3, acc[c], 0,0,0);
    acc[c] = __builtin_amdgcn_mfma_f32_16x16x32_bf16(a0, bl0, acc[c], 0,0,0);
    acc[c] = __builtin_amdgcn_mfma_f32_16x16x32_bf16(a1, bl1, acc[c], 0,0,0);
    acc[c] = __builtin_amdgcn_mfma_f32_16x16x32_bf16(a2, bl2, acc[c], 0,0,0);
    acc[c] = __builtin_amdgcn_mfma_f32_16x16x32_bf16(a3, bl3, acc[c], 0,0,0);
    bias[c] = Wc[FB2F + c*16 + lr];
  }
  int fl = *flag;
  #pragma unroll
  for(int r=0;r<4;r++){
    int orow = blockIdx.x*64 + w*16 + lg*4 + r;
    if(orow < NN){
      if(fl){
        float* op = (float*)outv + (size_t)orow*32 + lr;
        op[0]  = acc[0][r] + bias[0];
        op[16] = acc[1][r] + bias[1];
      } else {
        unsigned short* op = (unsigned short*)outv + (size_t)orow*32 + lr;
        op[0]  = f2us(acc[0][r] + bias[0]);
        op[16] = f2us(acc[1][r] + bias[1]);
      }
    }
  }
}

extern "C" void kernel_launch(void* const* d_in, const int* in_sizes, int n_in,
                              void* d_out, int out_size, void* d_ws, size_t ws_size,
                              hipStream_t stream){
  const void* x   = d_in[0];
  const int*  ei  = (const int*)d_in[1];
  const int* srcI = ei;        // edge_index[0]
  const int* dstI = ei + NE;   // edge_index[1]

  // workspace layout (bytes); ~43 MB + 80KB bf16 weight pool
  char*   base   = (char*)d_ws;
  int*    flag   = (int*)   (base + 0);          // 256
  float*  Wc     = (float*) (base + 256);        // 83840 -> 84096
  int*    bstart = (int*)   (base + 84224);      // 6256
  int*    cnt    = (int*)   (base + 90624);      // 1225392
  int*    tmpS   = (int*)   (base + 1316096);    // 1225392
  int*    bsum   = (int*)   (base + 2541568);    // 2048
  float*  dinv   = (float*) (base + 2545664);    // 400000
  int*    rowptr = (int*)   (base + 2945664);    // 400004
  int*    epk    = (int*)   (base + 3345792);    // 6400000
  int*    srcS   = (int*)   (base + 9745792);    // 6400000
  float2* xd     = (float2*)(base + 16145792);   // 800000
  bf16*   s      = (bf16*)  (base + 16945792);   // 12800000
  bf16*   h      = (bf16*)  (base + 29745792);   // 12800000 -> ends 42545792
  unsigned short* Wb = (unsigned short*)(base + 42545792);  // 81920 -> ends 42627712

  // merged init: edge histogram (blocks 0..195) + weight convert (blocks 196..276)
  k_init<<<NBB+CVB, 512, 0, stream>>>(
      (const unsigned short*)x,
      d_in[2], d_in[3], d_in[4], d_in[5], d_in[6],
      d_in[7], d_in[8], d_in[9], d_in[10], d_in[11], flag, Wc, Wb, dstI, cnt);

  // bucket-grouped build: scan (2 kernels) -> place -> in-bucket sort (+xd)
  k_scanA <<<SCANB, 1024, 0, stream>>>(cnt, tmpS, bsum);
  k_scanC <<<SCANB, 1024, 0, stream>>>(cnt, tmpS, bsum, bstart);
  k_bplace<<<NBB, 512, 0, stream>>>(srcI, dstI, cnt, epk);
  k_bsort <<<NBUK, 512, 0, stream>>>(bstart, epk, srcS, rowptr, dinv, x, flag, xd);

  // layer 1 (2 -> 64): fused propagate + transform + relu
  k_prop1<<<(NN+255)/256, 256, 0, stream>>>(rowptr, srcS, xd, Wc, dinv, h);

  // layer 2 (64 -> 64)
  k_transform64<<<NBUK, 256, 0, stream>>>(h, Wb+W2TH, Wb+W2TL, dinv, s);
  k_aggregate  <<<NN/8, 256, 0, stream>>>(rowptr, srcS, s, dinv, Wc+B2F, h);

  // layer 3 (64 -> 64)
  k_transform64<<<NBUK, 256, 0, stream>>>(h, Wb+W3TH, Wb+W3TL, dinv, s);
  k_aggregate  <<<NN/8, 256, 0, stream>>>(rowptr, srcS, s, dinv, Wc+B3F, h);

  // fused fc1+fc2 (MFMA, frag-contiguous weights, fc1 tile in LDS)
  k_fc<<<NBUK, 256, 0, stream>>>(h, Wb+F1TH, Wb+F1TL, Wb+F2TH, Wb+F2TL, Wc, flag, d_out);
}